// Round 4
// baseline (977.081 us; speedup 1.0000x reference)
//
#include <hip/hip_runtime.h>
#include <stdint.h>

#define Bd   128
#define Td   1000
#define INd  700
#define Hd   512
#define OUTd 20
#define Md   (Bd * Td)
#define KPAD 704                 // 22 * 32
#define KIT  22
#define KH   1408                // packed row: 2*KPAD halves (x1|x2 interleaved per k-tile)

typedef _Float16 f16;
typedef f16 f16x4 __attribute__((ext_vector_type(4)));
typedef f16 f16x8 __attribute__((ext_vector_type(8)));
typedef float f32x4 __attribute__((ext_vector_type(4)));
typedef float f32x16 __attribute__((ext_vector_type(16)));

// async global->LDS, 16B per lane; LDS dest must be wave-uniform base + lane*16
__device__ __forceinline__ void gld_lds16(const void* g, void* l) {
  __builtin_amdgcn_global_load_lds(
      (__attribute__((address_space(1))) void*)(g),
      (__attribute__((address_space(3))) void*)(l), 16, 0, 0);
}

// ---------------------------------------------------------------------------
// Pack src fp32 [nrows][700] -> dst f16 [nrows][22][8 chunks of 8 halves].
// Logical chunks 0..3 = f16(x), 4..7 = residual f16(x - f16(x)).
// Physical chunk = logical ^ (row & 7): XOR bank swizzle baked into the
// GLOBAL layout so linear global_load_lds staging lands a swizzled LDS image.
// ---------------------------------------------------------------------------
__global__ __launch_bounds__(256) void pack_kernel(
    const float* __restrict__ src, f16* __restrict__ dst, int nrows) {
  const int t = blockIdx.x * 256 + threadIdx.x;   // t = m*88 + kt*4 + lc
  if (t >= nrows * 88) return;
  const int m = t / 88;
  const int rem = t - m * 88;
  const int kt = rem >> 2;
  const int lc = rem & 3;
  const int k0 = kt * 32 + lc * 8;
  const float* sp = src + (size_t)m * INd + k0;
  float v[8];
  if (k0 + 8 <= INd) {
    const float4 v0 = *(const float4*)sp;
    const float4 v1 = *(const float4*)(sp + 4);
    v[0] = v0.x; v[1] = v0.y; v[2] = v0.z; v[3] = v0.w;
    v[4] = v1.x; v[5] = v1.y; v[6] = v1.z; v[7] = v1.w;
  } else {
#pragma unroll
    for (int u = 0; u < 8; ++u) v[u] = (k0 + u < INd) ? sp[u] : 0.f;
  }
  f16x8 h1, h2;
#pragma unroll
  for (int u = 0; u < 8; ++u) {
    const f16 a = (f16)v[u];
    h1[u] = a;
    h2[u] = (f16)(v[u] - (float)a);
  }
  const int s = m & 7;
  f16* out = dst + (size_t)m * KH + (size_t)kt * 64;
  *(f16x8*)(out + ((lc ^ s) << 3)) = h1;
  *(f16x8*)(out + (((lc + 4) ^ s) << 3)) = h2;
}

// ---------------------------------------------------------------------------
// GEMM1 (fast path): proj = X*W1^T + b1, 3-term f16 split via 32x32x16 MFMA.
// 256x256 tile, 512 threads = 8 waves (2M x 4N), wave tile 128x64 =
// 4 m-tiles x 2 n-tiles of 32x32. K-tile = 32 real k, split into two
// kk-halves (K=16 each). Each fragment read ONCE per K-tile (24 ds_read_b128
// per lane vs 48 with 16x16x32): LDS pipe load halved -> ~2300 cyc/tile.
// E/O fragment double-buffer pipelines ds_read under MFMA. ONE barrier per
// K-tile; staging for tile t+2 issued at t's tail into the just-drained
// buffer (full-tile HBM latency hiding).
// 32x32x16 frag layout: A row=lane&31, k=(lane>>5)*8+i (chunk (lane>>5));
// D col=lane&31, row=(reg&3)+8*(reg>>2)+4*(lane>>5).
// ---------------------------------------------------------------------------
#define SBAR __builtin_amdgcn_sched_barrier(0)

// load one kk-half's fragment set S: 8 A-frags + 4 B-frags (12 ds_read_b128)
#define LOAD_FR(S, O1, O2, AB, BB)                                      \
  _Pragma("unroll")                                                     \
  for (int mt = 0; mt < 4; ++mt) {                                      \
    const int rb = (wm0 + mt * 32 + l31) << 6;                          \
    a1##S[mt] = *(const f16x8*)&(AB)[rb + (O1)];                        \
    a2##S[mt] = *(const f16x8*)&(AB)[rb + (O2)];                        \
  }                                                                     \
  _Pragma("unroll")                                                     \
  for (int nt = 0; nt < 2; ++nt) {                                      \
    const int cb = (wn0 + nt * 32 + l31) << 6;                          \
    b1##S[nt] = *(const f16x8*)&(BB)[cb + (O1)];                        \
    b2##S[nt] = *(const f16x8*)&(BB)[cb + (O2)];                        \
  }

// 24 mfma_f32_32x32x16_f16 on fragment set S (3-term split)
#define MM(S)                                                           \
  __builtin_amdgcn_s_setprio(1);                                        \
  _Pragma("unroll")                                                     \
  for (int mt = 0; mt < 4; ++mt)                                        \
  _Pragma("unroll")                                                     \
  for (int nt = 0; nt < 2; ++nt) {                                      \
    f32x16 a = acc[mt][nt];                                             \
    a = __builtin_amdgcn_mfma_f32_32x32x16_f16(a1##S[mt], b1##S[nt], a, 0, 0, 0); \
    a = __builtin_amdgcn_mfma_f32_32x32x16_f16(a1##S[mt], b2##S[nt], a, 0, 0, 0); \
    a = __builtin_amdgcn_mfma_f32_32x32x16_f16(a2##S[mt], b1##S[nt], a, 0, 0, 0); \
    acc[mt][nt] = a;                                                    \
  }                                                                     \
  __builtin_amdgcn_s_setprio(0);

#define STAGE_AB(NB, GO)                                                \
  _Pragma("unroll")                                                     \
  for (int j = 0; j < 4; ++j) {                                         \
    gld_lds16(Ag + (size_t)j * (64 * KH) + (GO), &As[NB][tid * 8 + j * 4096]); \
    gld_lds16(Bg + (size_t)j * (64 * KH) + (GO), &Bs[NB][tid * 8 + j * 4096]); \
  }

__global__ __launch_bounds__(512, 2) void gemm1_kernel(
    const f16* __restrict__ Xp, const f16* __restrict__ Wp,
    const float* __restrict__ b1, float* __restrict__ proj) {
  __shared__ __align__(16) f16 As[2][256 * 64];   // 2 x 32 KB
  __shared__ __align__(16) f16 Bs[2][256 * 64];   // 2 x 32 KB
  const int tid = threadIdx.x;

  // bijective XCD swizzle: 1000 blocks = 8 XCDs x 125; each XCD gets a
  // compact m-range with both n-tiles.
  const int l = blockIdx.x;                // 0..999
  const int bb = (l & 7) * 125 + (l >> 3); // bijection on [0,1000)
  const int m0 = (bb >> 1) << 8;           // 500 m-tiles of 256
  const int n0 = (bb & 1) << 8;            // 2 n-tiles of 256

  // staging: thread -> (row = j*64 + (tid>>3), chunk = tid&7), 16B per issue
  const int srow = tid >> 3, sc = tid & 7;
  const f16* Ag = Xp + (size_t)(m0 + srow) * KH + (sc << 3);
  const f16* Bg = Wp + (size_t)(n0 + srow) * KH + (sc << 3);

  // wave tiling: 8 waves = 2M x 4N, per-wave 128x64 = 4mt x 2nt 32x32 tiles
  const int wv = tid >> 6, lane = tid & 63;
  const int wm0 = (wv >> 2) << 7;          // 0 or 128
  const int wn0 = (wv & 3) << 6;           // 0,64,128,192
  const int l31 = lane & 31;
  const int hk  = lane >> 5;               // k-chunk select within kk-half
  const int sw  = lane & 7;                // row&7 = lane&7 (rows are +l31)
  // packed-chunk offsets (halves within a 64-half row), XOR-swizzled:
  const int oE1 = (((0 + hk) ^ sw) << 3);  // kk=0,  x1
  const int oE2 = (((4 + hk) ^ sw) << 3);  // kk=0,  residual
  const int oO1 = (((2 + hk) ^ sw) << 3);  // kk=16, x1
  const int oO2 = (((6 + hk) ^ sw) << 3);  // kk=16, residual

  f32x16 acc[4][2];
#pragma unroll
  for (int i = 0; i < 4; ++i)
#pragma unroll
    for (int j = 0; j < 2; ++j) acc[i][j] = (f32x16)0.f;

  // fragment sets: E = kk0 of current tile, O = kk16
  f16x8 a1E[4], a2E[4], b1E[2], b2E[2];
  f16x8 a1O[4], a2O[4], b1O[2], b2O[2];

  // prologue: stage tile 0 -> buf0; drain; preload E(t0); stage tile 1 -> buf1
  STAGE_AB(0, 0);
  asm volatile("s_waitcnt vmcnt(0)" ::: "memory");
  __builtin_amdgcn_sched_barrier(0);
  __builtin_amdgcn_s_barrier();
  LOAD_FR(E, oE1, oE2, As[0], Bs[0]);
  STAGE_AB(1, 64);

#pragma unroll 1
  for (int t = 0; t < KIT; ++t) {
    const f16* Ac = As[t & 1];
    const f16* Bc = Bs[t & 1];
    const int nb = (t & 1) ^ 1;

    // ph0: issue O-frag reads (kk16), then MFMA on E (kk0)
    LOAD_FR(O, oO1, oO2, Ac, Bc);
    SBAR;
    MM(E);
    SBAR;

    // tail: single barrier per tile.
    //  - vmcnt(0): stages(t+1) landed in buf[nb]
    //  - lgkm(0): all reads of buf[cur] (incl. O-frags) complete -> safe to
    //    overwrite cur with stages(t+2) after the barrier
    if (t + 1 < KIT) {
      asm volatile("s_waitcnt vmcnt(0) lgkmcnt(0)" ::: "memory");
      __builtin_amdgcn_sched_barrier(0);
      __builtin_amdgcn_s_barrier();
      if (t + 2 < KIT) {
        const size_t go2 = (size_t)(t + 2) << 6;
        STAGE_AB(t & 1, go2);
      }
      LOAD_FR(E, oE1, oE2, As[nb], Bs[nb]);
    }
    SBAR;
    MM(O);
    SBAR;
  }

  // ---- epilogue: per 32x32 tile, D[row=(r&3)+8*(r>>2)+4*hk][col=l31] ----
#pragma unroll
  for (int nt = 0; nt < 2; ++nt) {
    const int n = n0 + wn0 + nt * 32 + l31;
    const float bias = b1[n];
#pragma unroll
    for (int mt = 0; mt < 4; ++mt) {
      const int mb = m0 + wm0 + mt * 32 + 4 * hk;
#pragma unroll
      for (int r = 0; r < 16; ++r) {
        const int m = mb + (r & 3) + 8 * (r >> 2);
        proj[(size_t)m * Hd + n] = acc[mt][nt][r] + bias;
      }
    }
  }
}

// ===========================================================================
// FALLBACK PATH (verbatim, used only if workspace too small for packed X)
// ===========================================================================
__global__ __launch_bounds__(256) void w1split_kernel(
    const float* __restrict__ W1, f16* __restrict__ W1a,
    f16* __restrict__ W1b) {
  const int idx = blockIdx.x * 256 + threadIdx.x;
  if (idx >= 512 * KPAD) return;
  const int n = idx / KPAD, k = idx - n * KPAD;
  const float v = (k < INd) ? W1[n * INd + k] : 0.f;
  const f16 h1 = (f16)v;
  const f16 h2 = (f16)(v - (float)h1);
  W1a[idx] = h1;
  W1b[idx] = h2;
}

__global__ __launch_bounds__(256) void gemm1_fb_kernel(
    const float* __restrict__ X, const f16* __restrict__ W1a,
    const f16* __restrict__ W1b, const float* __restrict__ b1,
    float* __restrict__ proj) {
  __shared__ __align__(16) f16 A1s[128 * 40];
  __shared__ __align__(16) f16 A2s[128 * 40];
  __shared__ __align__(16) f16 B1s[128 * 40];
  __shared__ __align__(16) f16 B2s[128 * 40];

  const int tid = threadIdx.x;
  const int n0 = blockIdx.x * 128;
  const int m0 = blockIdx.y * 128;

  const int srow = tid >> 1;
  const int skq  = (tid & 1) << 4;

  const float* Xp  = X + (size_t)(m0 + srow) * INd;
  const f16*   Bap = W1a + (size_t)(n0 + srow) * KPAD + skq;
  const f16*   Bbp = W1b + (size_t)(n0 + srow) * KPAD + skq;

  const int wv = tid >> 6, lane = tid & 63;
  const int wm0 = (wv >> 1) * 64, wn0 = (wv & 1) * 64;
  const int fr = lane & 15;
  const int fq = lane >> 4;

  f32x4 acc[4][4];
#pragma unroll
  for (int i = 0; i < 4; ++i)
#pragma unroll
    for (int j = 0; j < 4; ++j) acc[i][j] = (f32x4){0.f, 0.f, 0.f, 0.f};

  const float4 z4 = make_float4(0.f, 0.f, 0.f, 0.f);
  float4 ax[4];
  f16x8 bq1[2], bq2[2];

#pragma unroll
  for (int i = 0; i < 4; ++i) ax[i] = *(const float4*)(Xp + skq + 4 * i);
  bq1[0] = *(const f16x8*)(Bap);     bq1[1] = *(const f16x8*)(Bap + 8);
  bq2[0] = *(const f16x8*)(Bbp);     bq2[1] = *(const f16x8*)(Bbp + 8);

#pragma unroll 1
  for (int it = 0; it < KIT; ++it) {
    __syncthreads();
#pragma unroll
    for (int i = 0; i < 4; ++i) {
      const float4 v = ax[i];
      f16x4 h1, h2;
      h1.x = (f16)v.x; h2.x = (f16)(v.x - (float)h1.x);
      h1.y = (f16)v.y; h2.y = (f16)(v.y - (float)h1.y);
      h1.z = (f16)v.z; h2.z = (f16)(v.z - (float)h1.z);
      h1.w = (f16)v.w; h2.w = (f16)(v.w - (float)h1.w);
      *(f16x4*)&A1s[srow * 40 + skq + 4 * i] = h1;
      *(f16x4*)&A2s[srow * 40 + skq + 4 * i] = h2;
    }
    *(f16x8*)&B1s[srow * 40 + skq]     = bq1[0];
    *(f16x8*)&B1s[srow * 40 + skq + 8] = bq1[1];
    *(f16x8*)&B2s[srow * 40 + skq]     = bq2[0];
    *(f16x8*)&B2s[srow * 40 + skq + 8] = bq2[1];
    __syncthreads();
    if (it + 1 < KIT) {
      const int k0 = (it + 1) * 32;
#pragma unroll
      for (int i = 0; i < 4; ++i) {
        const int k = k0 + skq + 4 * i;
        ax[i] = (k + 4 <= INd) ? *(const float4*)(Xp + k) : z4;
      }
      bq1[0] = *(const f16x8*)(Bap + k0);
      bq1[1] = *(const f16x8*)(Bap + k0 + 8);
      bq2[0] = *(const f16x8*)(Bbp + k0);
      bq2[1] = *(const f16x8*)(Bbp + k0 + 8);
    }
    f16x8 a1f[4], a2f[4], b1f[4], b2f[4];
#pragma unroll
    for (int mi = 0; mi < 4; ++mi) {
      const int off = (wm0 + mi * 16 + fr) * 40 + fq * 8;
      a1f[mi] = *(const f16x8*)&A1s[off];
      a2f[mi] = *(const f16x8*)&A2s[off];
    }
#pragma unroll
    for (int ni = 0; ni < 4; ++ni) {
      const int off = (wn0 + ni * 16 + fr) * 40 + fq * 8;
      b1f[ni] = *(const f16x8*)&B1s[off];
      b2f[ni] = *(const f16x8*)&B2s[off];
    }
#pragma unroll
    for (int mi = 0; mi < 4; ++mi)
#pragma unroll
      for (int ni = 0; ni < 4; ++ni) {
        acc[mi][ni] = __builtin_amdgcn_mfma_f32_16x16x32_f16(
            a1f[mi], b1f[ni], acc[mi][ni], 0, 0, 0);
        acc[mi][ni] = __builtin_amdgcn_mfma_f32_16x16x32_f16(
            a1f[mi], b2f[ni], acc[mi][ni], 0, 0, 0);
        acc[mi][ni] = __builtin_amdgcn_mfma_f32_16x16x32_f16(
            a2f[mi], b1f[ni], acc[mi][ni], 0, 0, 0);
      }
  }

#pragma unroll
  for (int ni = 0; ni < 4; ++ni) {
    const int n = n0 + wn0 + ni * 16 + fr;
    const float bias = b1[n];
#pragma unroll
    for (int mi = 0; mi < 4; ++mi) {
      const int mb = m0 + wm0 + mi * 16 + fq * 4;
      float* p = proj + (size_t)mb * Hd + n;
#pragma unroll
      for (int r = 0; r < 4; ++r)
        p[(size_t)r * Hd] = acc[mi][ni][r] + bias;
    }
  }
}

// ---------------------------------------------------------------------------
// Scan1: per-(b,h) LIF + dendritic filter; emit spike bitmasks.
// Prefetch ring is STATICALLY indexed (manual 4x unroll, rule #20).
// ---------------------------------------------------------------------------
#define S1_PHASE(QC, QN, T0)                                      \
  {                                                               \
    const int tp_ = (T0) + 24;                                    \
    _Pragma("unroll")                                             \
    for (int u = 0; u < 8; ++u) {                                 \
      const int tt = (tp_ + u < Td) ? (tp_ + u) : (Td - 1);       \
      buf[QN][u] = pp[(size_t)tt * Hd];                           \
    }                                                             \
    _Pragma("unroll")                                             \
    for (int u = 0; u < 8; ++u) {                                 \
      const float pv = buf[QC][u];                                \
      d = bn * d + ombn * pv;                                     \
      mem = am * mem + omam * d - s;                              \
      const bool fire = mem > 1.0f;                               \
      s = fire ? 1.f : 0.f;                                       \
      const unsigned long long msk = __ballot(fire);              \
      if (lane == 0) sp[(size_t)((T0) + u) * 8] = msk;            \
    }                                                             \
  }

__global__ __launch_bounds__(256) void scan1_kernel(
    const float* __restrict__ proj, const float* __restrict__ tau_m1,
    const float* __restrict__ tau_n1, const float* __restrict__ mem1_0,
    unsigned long long* __restrict__ spk) {
  const int gid = blockIdx.x * 256 + threadIdx.x;
  const int b = gid >> 9;
  const int h = gid & 511;
  const float am = 1.f / (1.f + expf(-tau_m1[h]));
  const float bn = 1.f / (1.f + expf(-tau_n1[h]));
  const float omam = 1.f - am, ombn = 1.f - bn;
  float mem = mem1_0[(b << 9) | h];
  float d = 0.f, s = 0.f;
  const float* pp = proj + (size_t)b * Td * Hd + h;
  unsigned long long* sp = spk + (size_t)b * Td * 8 + (h >> 6);
  const int lane = threadIdx.x & 63;

  float buf[4][8];
#pragma unroll
  for (int q = 0; q < 3; ++q)
#pragma unroll
    for (int u = 0; u < 8; ++u)
      buf[q][u] = pp[(size_t)(q * 8 + u) * Hd];

#pragma unroll 1
  for (int t0 = 0; t0 < 992; t0 += 32) {
    S1_PHASE(0, 3, t0);
    S1_PHASE(1, 0, t0 + 8);
    S1_PHASE(2, 1, t0 + 16);
    S1_PHASE(3, 2, t0 + 24);
  }
  S1_PHASE(0, 3, 992);   // t = 992..999
}

// ---------------------------------------------------------------------------
// GEMM2: R[m][o] = b2[o] + sum over set spike bits h of W2[o][h].
// ---------------------------------------------------------------------------
__global__ __launch_bounds__(256) void gemm2_kernel(
    const unsigned long long* __restrict__ spk, const float* __restrict__ W2,
    const float* __restrict__ b2, float* __restrict__ R, int Mtotal) {
  __shared__ float W2s[Hd * OUTd];
  const int tid = threadIdx.x;
  for (int idx = tid; idx < Hd * OUTd; idx += 256) {
    const int h = idx / OUTd, o = idx - h * OUTd;
    W2s[idx] = W2[o * Hd + h];
  }
  __syncthreads();
  const int wave = tid >> 6, lane = tid & 63;
  const int mg = lane / OUTd;
  const int o = lane - mg * OUTd;
  if (mg >= 3) return;
  const float bias = b2[o];
  const int mbase = blockIdx.x * 96 + wave * 24 + mg;
#pragma unroll 1
  for (int i = 0; i < 8; ++i) {
    const int m = mbase + i * 3;
    if (m >= Mtotal) break;
    float r = bias;
    const unsigned long long* mp = spk + (size_t)m * 8;
#pragma unroll
    for (int c = 0; c < 8; ++c) {
      unsigned long long mask = mp[c];
      const float* wrow = W2s + (c << 6) * OUTd + o;
      while (mask) {
        const int j = __builtin_ctzll(mask);
        mask &= mask - 1;
        r += wrow[j * OUTd];
      }
    }
    R[(size_t)m * OUTd + o] = r;
  }
}

// ---------------------------------------------------------------------------
// Scan2: per-(b,o) leaky readout, chunked parallel scan (8 x 125).
// ---------------------------------------------------------------------------
__global__ __launch_bounds__(256) void scan2_kernel(
    const float* __restrict__ R, const float* __restrict__ tau_m2,
    const float* __restrict__ mem2_0, float* __restrict__ out) {
  __shared__ float leS[8][20];
  __shared__ float stS[8][20];
  const int b = blockIdx.x;
  const int tid = threadIdx.x;
  const int c = tid / OUTd;
  const int o = tid - c * OUTd;
  const bool active = tid < 160;
  float a2 = 0.f, oma2 = 0.f;
  if (active) {
    a2 = 1.f / (1.f + expf(-tau_m2[o]));
    oma2 = 1.f - a2;
  }
  const float* Rb = R + (size_t)b * Td * OUTd;
  float* Ob = out + (size_t)b * Td * OUTd;
  const int t0 = c * 125;

  if (active) {
    float m = 0.f;
    for (int u = 0; u < 125; ++u)
      m = a2 * m + oma2 * Rb[(size_t)(t0 + u) * OUTd + o];
    leS[c][o] = m;
  }
  __syncthreads();
  if (tid < OUTd) {
    const float a = 1.f / (1.f + expf(-tau_m2[tid]));
    float aL = 1.f;
    for (int i = 0; i < 125; ++i) aL *= a;
    float m = mem2_0[b * OUTd + tid];
    for (int cc = 0; cc < 8; ++cc) {
      stS[cc][tid] = m;
      m = aL * m + leS[cc][tid];
    }
  }
  __syncthreads();
  if (active) {
    float m = stS[c][o];
    for (int u = 0; u < 125; ++u) {
      m = a2 * m + oma2 * Rb[(size_t)(t0 + u) * OUTd + o];
      Ob[(size_t)(t0 + u) * OUTd + o] = m;
    }
  }
}

extern "C" void kernel_launch(void* const* d_in, const int* in_sizes, int n_in,
                              void* d_out, int out_size, void* d_ws, size_t ws_size,
                              hipStream_t stream) {
  const float* x      = (const float*)d_in[0];
  const float* W1     = (const float*)d_in[1];
  const float* b1     = (const float*)d_in[2];
  const float* tau_m1 = (const float*)d_in[3];
  const float* tau_n1 = (const float*)d_in[4];
  const float* W2     = (const float*)d_in[5];
  const float* b2     = (const float*)d_in[6];
  const float* tau_m2 = (const float*)d_in[7];
  const float* mem1_0 = (const float*)d_in[8];
  const float* mem2_0 = (const float*)d_in[9];
  float* out = (float*)d_out;

  const size_t proj_b = (size_t)Md * Hd * sizeof(float);            // 262.1 MB
  const size_t xp_b   = (size_t)Md * KH * sizeof(f16);              // 360.4 MB
  const size_t wp_b   = (size_t)512 * KH * sizeof(f16);             // 1.44 MB
  const size_t spk_b  = (size_t)Md * 8 * sizeof(unsigned long long);// 8.2 MB

  float* proj = (float*)d_ws;

  if (ws_size >= proj_b + xp_b + wp_b) {
    // Fast path: proj | Xp | Wp.  spk+R overlay the Xp region after gemm1.
    f16* Xpk = (f16*)((char*)d_ws + proj_b);
    f16* Wpk = (f16*)((char*)d_ws + proj_b + xp_b);
    unsigned long long* spk = (unsigned long long*)((char*)d_ws + proj_b);
    float* R = (float*)((char*)d_ws + proj_b + spk_b);

    pack_kernel<<<dim3(Md * 88 / 256), 256, 0, stream>>>(x, Xpk, Md);
    pack_kernel<<<dim3(512 * 88 / 256), 256, 0, stream>>>(W1, Wpk, 512);
    gemm1_kernel<<<dim3((Hd / 256) * (Md / 256)), 512, 0, stream>>>(Xpk, Wpk,
                                                                    b1, proj);
    scan1_kernel<<<dim3(Bd * Hd / 256), 256, 0, stream>>>(proj, tau_m1, tau_n1,
                                                          mem1_0, spk);
    gemm2_kernel<<<dim3((Md + 95) / 96), 256, 0, stream>>>(spk, W2, b2, R, Md);
    scan2_kernel<<<dim3(Bd), 256, 0, stream>>>(R, tau_m2, mem2_0, out);
  } else {
    // Fallback (previous verified layout): proj | spk | R, W1 splits inside R.
    unsigned long long* spk =
        (unsigned long long*)((char*)d_ws + proj_b);
    float* R = (float*)((char*)spk + spk_b);
    f16* W1a = (f16*)R;
    f16* W1b = W1a + 512 * KPAD;

    w1split_kernel<<<dim3((512 * KPAD + 255) / 256), 256, 0, stream>>>(W1, W1a,
                                                                       W1b);
    gemm1_fb_kernel<<<dim3(Hd / 128, Md / 128), 256, 0, stream>>>(x, W1a, W1b,
                                                                  b1, proj);
    scan1_kernel<<<dim3(Bd * Hd / 256), 256, 0, stream>>>(proj, tau_m1, tau_n1,
                                                          mem1_0, spk);
    gemm2_kernel<<<dim3((Md + 95) / 96), 256, 0, stream>>>(spk, W2, b2, R, Md);
    scan2_kernel<<<dim3(Bd), 256, 0, stream>>>(R, tau_m2, mem2_0, out);
  }
}

// Round 5
// 894.219 us; speedup vs baseline: 1.0927x; 1.0927x over previous
//
#include <hip/hip_runtime.h>
#include <stdint.h>

#define Bd   128
#define Td   1000
#define INd  700
#define Hd   512
#define OUTd 20
#define Md   (Bd * Td)
#define KPAD 704                 // 22 * 32
#define KIT  22
#define KH   1408                // packed row: 2*KPAD halves (x1|x2 interleaved per k-tile)

typedef _Float16 f16;
typedef f16 f16x4 __attribute__((ext_vector_type(4)));
typedef f16 f16x8 __attribute__((ext_vector_type(8)));
typedef float f32x4 __attribute__((ext_vector_type(4)));

// async global->LDS, 16B per lane; LDS dest must be wave-uniform base + lane*16
__device__ __forceinline__ void gld_lds16(const void* g, void* l) {
  __builtin_amdgcn_global_load_lds(
      (__attribute__((address_space(1))) void*)(g),
      (__attribute__((address_space(3))) void*)(l), 16, 0, 0);
}

// ---------------------------------------------------------------------------
// Pack fp32 rows -> f16 [row][22][8 chunks of 8 halves], chunks 0..3 = f16(x),
// 4..7 = residual; physical chunk = logical ^ (row&7) (bank swizzle baked into
// global layout). ONE launch packs both X (Md rows) and W1 (512 rows).
// ---------------------------------------------------------------------------
__global__ __launch_bounds__(256) void pack_kernel(
    const float* __restrict__ x, const float* __restrict__ W1,
    f16* __restrict__ Xp, f16* __restrict__ Wp) {
  int t = blockIdx.x * 256 + threadIdx.x;   // t = row*88 + kt*4 + lc
  const int xcnt = Md * 88;
  const float* src;
  f16* dst;
  if (t < xcnt) {
    src = x; dst = Xp;
  } else {
    t -= xcnt;
    if (t >= 512 * 88) return;
    src = W1; dst = Wp;
  }
  const int m = t / 88;
  const int rem = t - m * 88;
  const int kt = rem >> 2;
  const int lc = rem & 3;
  const int k0 = kt * 32 + lc * 8;
  const float* sp = src + (size_t)m * INd + k0;
  float v[8];
  if (k0 + 8 <= INd) {
    const float4 v0 = *(const float4*)sp;
    const float4 v1 = *(const float4*)(sp + 4);
    v[0] = v0.x; v[1] = v0.y; v[2] = v0.z; v[3] = v0.w;
    v[4] = v1.x; v[5] = v1.y; v[6] = v1.z; v[7] = v1.w;
  } else {
#pragma unroll
    for (int u = 0; u < 8; ++u) v[u] = (k0 + u < INd) ? sp[u] : 0.f;
  }
  f16x8 h1, h2;
#pragma unroll
  for (int u = 0; u < 8; ++u) {
    const f16 a = (f16)v[u];
    h1[u] = a;
    h2[u] = (f16)(v[u] - (float)a);
  }
  const int s = m & 7;
  f16* out = dst + (size_t)m * KH + (size_t)kt * 64;
  *(f16x8*)(out + ((lc ^ s) << 3)) = h1;
  *(f16x8*)(out + (((lc + 4) ^ s) << 3)) = h2;
}

// ---------------------------------------------------------------------------
// GEMM1 (fast path, r3-verified: 278us, 0 conflicts, MfmaUtil 44%):
// proj = X*W1^T + b1, 3-term f16 split MFMA (16x16x32).
// 256x256 tile, 512 threads = 8 waves (2M x 4N), wave tile 128x64.
// Software-pipelined: phase p issues phase p+1's 12 ds_read_b128 into the
// alternate statically-named frag set BEFORE phase p's 24 MFMA.
// ONE barrier per K-tile (staging handoff at phase 3).
// ---------------------------------------------------------------------------
#define SBAR __builtin_amdgcn_sched_barrier(0)

#define LOAD_FRAGS(S, MH, NH, AB, BB)                                   \
  _Pragma("unroll")                                                     \
  for (int mi = 0; mi < 4; ++mi) {                                      \
    const int rb = (wm0 + (MH) * 64 + mi * 16 + fr) << 6;               \
    a1##S[mi] = *(const f16x8*)&(AB)[rb + o1];                          \
    a2##S[mi] = *(const f16x8*)&(AB)[rb + o2];                          \
  }                                                                     \
  _Pragma("unroll")                                                     \
  for (int nj = 0; nj < 2; ++nj) {                                      \
    const int cb = (wn0 + (NH) * 32 + nj * 16 + fr) << 6;               \
    b1##S[nj] = *(const f16x8*)&(BB)[cb + o1];                          \
    b2##S[nj] = *(const f16x8*)&(BB)[cb + o2];                          \
  }

#define MFMA_PHASE(S, MH, NH)                                           \
  __builtin_amdgcn_s_setprio(1);                                        \
  _Pragma("unroll")                                                     \
  for (int mi = 0; mi < 4; ++mi)                                        \
  _Pragma("unroll")                                                     \
  for (int nj = 0; nj < 2; ++nj) {                                      \
    f32x4 a = acc[(MH) * 4 + mi][(NH) * 2 + nj];                        \
    a = __builtin_amdgcn_mfma_f32_16x16x32_f16(a1##S[mi], b1##S[nj], a, 0, 0, 0); \
    a = __builtin_amdgcn_mfma_f32_16x16x32_f16(a1##S[mi], b2##S[nj], a, 0, 0, 0); \
    a = __builtin_amdgcn_mfma_f32_16x16x32_f16(a2##S[mi], b1##S[nj], a, 0, 0, 0); \
    acc[(MH) * 4 + mi][(NH) * 2 + nj] = a;                              \
  }                                                                     \
  __builtin_amdgcn_s_setprio(0);

#define STAGE_A(NB, GO)                                                 \
  _Pragma("unroll")                                                     \
  for (int j = 0; j < 4; ++j)                                           \
    gld_lds16(Ag + (size_t)j * (64 * KH) + (GO), &As[NB][tid * 8 + j * 4096]);

#define STAGE_B(NB, GO)                                                 \
  _Pragma("unroll")                                                     \
  for (int j = 0; j < 4; ++j)                                           \
    gld_lds16(Bg + (size_t)j * (64 * KH) + (GO), &Bs[NB][tid * 8 + j * 4096]);

__global__ __launch_bounds__(512, 2) void gemm1_kernel(
    const f16* __restrict__ Xp, const f16* __restrict__ Wp,
    const float* __restrict__ b1, float* __restrict__ proj) {
  __shared__ __align__(16) f16 As[2][256 * 64];   // 2 x 32 KB
  __shared__ __align__(16) f16 Bs[2][256 * 64];   // 2 x 32 KB
  const int tid = threadIdx.x;

  // bijective XCD swizzle: 1000 blocks = 8 XCDs x 125
  const int l = blockIdx.x;                // 0..999
  const int bb = (l & 7) * 125 + (l >> 3); // bijection on [0,1000)
  const int m0 = (bb >> 1) << 8;           // 500 m-tiles of 256
  const int n0 = (bb & 1) << 8;            // 2 n-tiles of 256

  // staging: thread -> (row = j*64 + (tid>>3), chunk = tid&7), 16B per issue
  const int srow = tid >> 3, sc = tid & 7;
  const f16* Ag = Xp + (size_t)(m0 + srow) * KH + (sc << 3);
  const f16* Bg = Wp + (size_t)(n0 + srow) * KH + (sc << 3);

  // wave tiling: 8 waves = 2M x 4N, per-wave 128x64 = 8mi x 4ni 16x16 tiles
  const int wv = tid >> 6, lane = tid & 63;
  const int wm0 = (wv >> 2) << 7;          // 0 or 128
  const int wn0 = (wv & 3) << 6;           // 0,64,128,192
  const int fr = lane & 15;
  const int fq = lane >> 4;
  const int swz = (fr & 7) << 4;                 // byte XOR (row&7 within tile)
  const int o1 = ((fq << 4) ^ swz) >> 1;         // half-off of x1/w1 chunk
  const int o2 = (((fq + 4) << 4) ^ swz) >> 1;   // half-off of residual chunk

  f32x4 acc[8][4];
#pragma unroll
  for (int i = 0; i < 8; ++i)
#pragma unroll
    for (int j = 0; j < 4; ++j) acc[i][j] = (f32x4){0.f, 0.f, 0.f, 0.f};

  // double-buffered fragment sets (E used by ph0/ph2, O by ph1/ph3)
  f16x8 a1E[4], a2E[4], b1E[2], b2E[2];
  f16x8 a1O[4], a2O[4], b1O[2], b2O[2];

  // prologue: stage k-tile 0 into buffer 0, then preload ph0 frags
  STAGE_A(0, 0);
  STAGE_B(0, 0);
  asm volatile("s_waitcnt vmcnt(0)" ::: "memory");
  __builtin_amdgcn_sched_barrier(0);
  __builtin_amdgcn_s_barrier();
  LOAD_FRAGS(E, 0, 0, As[0], Bs[0]);

#pragma unroll 1
  for (int t = 0; t < KIT; ++t) {
    const f16* Ac = As[t & 1];
    const f16* Bc = Bs[t & 1];
    const int nb = (t & 1) ^ 1;
    const bool pf = (t + 1 < KIT);
    const size_t go = (size_t)(t + 1) << 6;   // halves offset within row

    // ---- ph0: load ph1 frags; issue A-stage; MFMA quadrant (0,0) ----
    LOAD_FRAGS(O, 0, 1, Ac, Bc);
    if (pf) { STAGE_A(nb, go); }
    SBAR;
    MFMA_PHASE(E, 0, 0);
    SBAR;
    // ---- ph1: load ph2 frags; issue B-stage; MFMA (0,1) ----
    LOAD_FRAGS(E, 1, 0, Ac, Bc);
    if (pf) { STAGE_B(nb, go); }
    SBAR;
    MFMA_PHASE(O, 0, 1);
    SBAR;
    // ---- ph2: load ph3 frags; MFMA (1,0) ----
    LOAD_FRAGS(O, 1, 1, Ac, Bc);
    SBAR;
    MFMA_PHASE(E, 1, 0);
    SBAR;
    // ---- ph3: staging handoff barrier; load next tile's ph0; MFMA (1,1) ----
    if (pf) {
      asm volatile("s_waitcnt vmcnt(0) lgkmcnt(0)" ::: "memory");
      __builtin_amdgcn_sched_barrier(0);
      __builtin_amdgcn_s_barrier();
      LOAD_FRAGS(E, 0, 0, As[nb], Bs[nb]);
    }
    SBAR;
    MFMA_PHASE(O, 1, 1);
    SBAR;
  }

  // ---- epilogue: D[row=fq*4+r][col=fr] per 16x16 tile, + bias ----
#pragma unroll
  for (int ni = 0; ni < 4; ++ni) {
    const int n = n0 + wn0 + ni * 16 + fr;
    const float bias = b1[n];
#pragma unroll
    for (int mi = 0; mi < 8; ++mi) {
      const int mb = m0 + wm0 + mi * 16 + (fq << 2);
      float* p = proj + (size_t)mb * Hd + n;
#pragma unroll
      for (int rr = 0; rr < 4; ++rr)
        p[(size_t)rr * Hd] = acc[mi][ni][rr] + bias;
    }
  }
}

// ===========================================================================
// FALLBACK PATH (verbatim, used only if workspace too small for packed X)
// ===========================================================================
__global__ __launch_bounds__(256) void w1split_kernel(
    const float* __restrict__ W1, f16* __restrict__ W1a,
    f16* __restrict__ W1b) {
  const int idx = blockIdx.x * 256 + threadIdx.x;
  if (idx >= 512 * KPAD) return;
  const int n = idx / KPAD, k = idx - n * KPAD;
  const float v = (k < INd) ? W1[n * INd + k] : 0.f;
  const f16 h1 = (f16)v;
  const f16 h2 = (f16)(v - (float)h1);
  W1a[idx] = h1;
  W1b[idx] = h2;
}

__global__ __launch_bounds__(256) void gemm1_fb_kernel(
    const float* __restrict__ X, const f16* __restrict__ W1a,
    const f16* __restrict__ W1b, const float* __restrict__ b1,
    float* __restrict__ proj) {
  __shared__ __align__(16) f16 A1s[128 * 40];
  __shared__ __align__(16) f16 A2s[128 * 40];
  __shared__ __align__(16) f16 B1s[128 * 40];
  __shared__ __align__(16) f16 B2s[128 * 40];

  const int tid = threadIdx.x;
  const int n0 = blockIdx.x * 128;
  const int m0 = blockIdx.y * 128;

  const int srow = tid >> 1;
  const int skq  = (tid & 1) << 4;

  const float* Xp  = X + (size_t)(m0 + srow) * INd;
  const f16*   Bap = W1a + (size_t)(n0 + srow) * KPAD + skq;
  const f16*   Bbp = W1b + (size_t)(n0 + srow) * KPAD + skq;

  const int wv = tid >> 6, lane = tid & 63;
  const int wm0 = (wv >> 1) * 64, wn0 = (wv & 1) * 64;
  const int fr = lane & 15;
  const int fq = lane >> 4;

  f32x4 acc[4][4];
#pragma unroll
  for (int i = 0; i < 4; ++i)
#pragma unroll
    for (int j = 0; j < 4; ++j) acc[i][j] = (f32x4){0.f, 0.f, 0.f, 0.f};

  const float4 z4 = make_float4(0.f, 0.f, 0.f, 0.f);
  float4 ax[4];
  f16x8 bq1[2], bq2[2];

#pragma unroll
  for (int i = 0; i < 4; ++i) ax[i] = *(const float4*)(Xp + skq + 4 * i);
  bq1[0] = *(const f16x8*)(Bap);     bq1[1] = *(const f16x8*)(Bap + 8);
  bq2[0] = *(const f16x8*)(Bbp);     bq2[1] = *(const f16x8*)(Bbp + 8);

#pragma unroll 1
  for (int it = 0; it < KIT; ++it) {
    __syncthreads();
#pragma unroll
    for (int i = 0; i < 4; ++i) {
      const float4 v = ax[i];
      f16x4 h1, h2;
      h1.x = (f16)v.x; h2.x = (f16)(v.x - (float)h1.x);
      h1.y = (f16)v.y; h2.y = (f16)(v.y - (float)h1.y);
      h1.z = (f16)v.z; h2.z = (f16)(v.z - (float)h1.z);
      h1.w = (f16)v.w; h2.w = (f16)(v.w - (float)h1.w);
      *(f16x4*)&A1s[srow * 40 + skq + 4 * i] = h1;
      *(f16x4*)&A2s[srow * 40 + skq + 4 * i] = h2;
    }
    *(f16x8*)&B1s[srow * 40 + skq]     = bq1[0];
    *(f16x8*)&B1s[srow * 40 + skq + 8] = bq1[1];
    *(f16x8*)&B2s[srow * 40 + skq]     = bq2[0];
    *(f16x8*)&B2s[srow * 40 + skq + 8] = bq2[1];
    __syncthreads();
    if (it + 1 < KIT) {
      const int k0 = (it + 1) * 32;
#pragma unroll
      for (int i = 0; i < 4; ++i) {
        const int k = k0 + skq + 4 * i;
        ax[i] = (k + 4 <= INd) ? *(const float4*)(Xp + k) : z4;
      }
      bq1[0] = *(const f16x8*)(Bap + k0);
      bq1[1] = *(const f16x8*)(Bap + k0 + 8);
      bq2[0] = *(const f16x8*)(Bbp + k0);
      bq2[1] = *(const f16x8*)(Bbp + k0 + 8);
    }
    f16x8 a1f[4], a2f[4], b1f[4], b2f[4];
#pragma unroll
    for (int mi = 0; mi < 4; ++mi) {
      const int off = (wm0 + mi * 16 + fr) * 40 + fq * 8;
      a1f[mi] = *(const f16x8*)&A1s[off];
      a2f[mi] = *(const f16x8*)&A2s[off];
    }
#pragma unroll
    for (int ni = 0; ni < 4; ++ni) {
      const int off = (wn0 + ni * 16 + fr) * 40 + fq * 8;
      b1f[ni] = *(const f16x8*)&B1s[off];
      b2f[ni] = *(const f16x8*)&B2s[off];
    }
#pragma unroll
    for (int mi = 0; mi < 4; ++mi)
#pragma unroll
      for (int ni = 0; ni < 4; ++ni) {
        acc[mi][ni] = __builtin_amdgcn_mfma_f32_16x16x32_f16(
            a1f[mi], b1f[ni], acc[mi][ni], 0, 0, 0);
        acc[mi][ni] = __builtin_amdgcn_mfma_f32_16x16x32_f16(
            a1f[mi], b2f[ni], acc[mi][ni], 0, 0, 0);
        acc[mi][ni] = __builtin_amdgcn_mfma_f32_16x16x32_f16(
            a2f[mi], b1f[ni], acc[mi][ni], 0, 0, 0);
      }
  }

#pragma unroll
  for (int ni = 0; ni < 4; ++ni) {
    const int n = n0 + wn0 + ni * 16 + fr;
    const float bias = b1[n];
#pragma unroll
    for (int mi = 0; mi < 4; ++mi) {
      const int mb = m0 + wm0 + mi * 16 + fq * 4;
      float* p = proj + (size_t)mb * Hd + n;
#pragma unroll
      for (int r = 0; r < 4; ++r)
        p[(size_t)r * Hd] = acc[mi][ni][r] + bias;
    }
  }
}

// ---------------------------------------------------------------------------
// Scan1: per-(b,h) LIF + dendritic filter; emit spike bitmasks.
// 8-slot, 56-step-ahead register prefetch ring, STATICALLY indexed (rule #20).
// ~56 outstanding load instrs/wave (vmcnt limit 63); with 4 waves/CU this puts
// ~57 KB in flight per CU -> covers 900-cyc HBM latency at full BW.
// ---------------------------------------------------------------------------
#define S1_PHASE(QC, QN, T0)                                      \
  {                                                               \
    const int tp_ = (T0) + 56;                                    \
    _Pragma("unroll")                                             \
    for (int u = 0; u < 8; ++u) {                                 \
      const int tt = (tp_ + u < Td) ? (tp_ + u) : (Td - 1);       \
      buf[QN][u] = pp[(size_t)tt * Hd];                           \
    }                                                             \
    _Pragma("unroll")                                             \
    for (int u = 0; u < 8; ++u) {                                 \
      const float pv = buf[QC][u];                                \
      d = bn * d + ombn * pv;                                     \
      mem = am * mem + omam * d - s;                              \
      const bool fire = mem > 1.0f;                               \
      s = fire ? 1.f : 0.f;                                       \
      const unsigned long long msk = __ballot(fire);              \
      if (lane == 0) sp[(size_t)((T0) + u) * 8] = msk;            \
    }                                                             \
  }

__global__ __launch_bounds__(256) void scan1_kernel(
    const float* __restrict__ proj, const float* __restrict__ tau_m1,
    const float* __restrict__ tau_n1, const float* __restrict__ mem1_0,
    unsigned long long* __restrict__ spk) {
  const int gid = blockIdx.x * 256 + threadIdx.x;
  const int b = gid >> 9;
  const int h = gid & 511;
  const float am = 1.f / (1.f + expf(-tau_m1[h]));
  const float bn = 1.f / (1.f + expf(-tau_n1[h]));
  const float omam = 1.f - am, ombn = 1.f - bn;
  float mem = mem1_0[(b << 9) | h];
  float d = 0.f, s = 0.f;
  const float* pp = proj + (size_t)b * Td * Hd + h;
  unsigned long long* sp = spk + (size_t)b * Td * 8 + (h >> 6);
  const int lane = threadIdx.x & 63;

  float buf[8][8];
#pragma unroll
  for (int q = 0; q < 7; ++q)
#pragma unroll
    for (int u = 0; u < 8; ++u)
      buf[q][u] = pp[(size_t)(q * 8 + u) * Hd];

#pragma unroll 1
  for (int t0 = 0; t0 < 960; t0 += 64) {
    S1_PHASE(0, 7, t0);
    S1_PHASE(1, 0, t0 + 8);
    S1_PHASE(2, 1, t0 + 16);
    S1_PHASE(3, 2, t0 + 24);
    S1_PHASE(4, 3, t0 + 32);
    S1_PHASE(5, 4, t0 + 40);
    S1_PHASE(6, 5, t0 + 48);
    S1_PHASE(7, 6, t0 + 56);
  }
  // tail: t = 960..999 (prefetches clamp to Td-1; slots unused after)
  S1_PHASE(0, 7, 960);
  S1_PHASE(1, 0, 968);
  S1_PHASE(2, 1, 976);
  S1_PHASE(3, 2, 984);
  S1_PHASE(4, 3, 992);
}

// ---------------------------------------------------------------------------
// GEMM2: R[m][o] = b2[o] + sum over set spike bits h of W2[o][h].
// All 8 masks prefetched to registers before the walk (one latency).
// ---------------------------------------------------------------------------
__global__ __launch_bounds__(256) void gemm2_kernel(
    const unsigned long long* __restrict__ spk, const float* __restrict__ W2,
    const float* __restrict__ b2, float* __restrict__ R, int Mtotal) {
  __shared__ float W2s[Hd * OUTd];
  const int tid = threadIdx.x;
  for (int idx = tid; idx < Hd * OUTd; idx += 256) {
    const int h = idx / OUTd, o = idx - h * OUTd;
    W2s[idx] = W2[o * Hd + h];
  }
  __syncthreads();
  const int wave = tid >> 6, lane = tid & 63;
  const int mg = lane / OUTd;
  const int o = lane - mg * OUTd;
  if (mg >= 3) return;
  const float bias = b2[o];
  const int mbase = blockIdx.x * 96 + wave * 24 + mg;
#pragma unroll 1
  for (int i = 0; i < 8; ++i) {
    const int m = mbase + i * 3;
    if (m >= Mtotal) break;
    const unsigned long long* mp = spk + (size_t)m * 8;
    unsigned long long mk[8];
#pragma unroll
    for (int c = 0; c < 8; ++c) mk[c] = mp[c];
    float r = bias;
#pragma unroll
    for (int c = 0; c < 8; ++c) {
      unsigned long long mask = mk[c];
      const float* wrow = W2s + (c << 6) * OUTd + o;
      while (mask) {
        const int j = __builtin_ctzll(mask);
        mask &= mask - 1;
        r += wrow[j * OUTd];
      }
    }
    R[(size_t)m * OUTd + o] = r;
  }
}

// ---------------------------------------------------------------------------
// Scan2: per-(b,o) leaky readout, chunked parallel scan (8 x 125).
// ---------------------------------------------------------------------------
__global__ __launch_bounds__(256) void scan2_kernel(
    const float* __restrict__ R, const float* __restrict__ tau_m2,
    const float* __restrict__ mem2_0, float* __restrict__ out) {
  __shared__ float leS[8][20];
  __shared__ float stS[8][20];
  const int b = blockIdx.x;
  const int tid = threadIdx.x;
  const int c = tid / OUTd;
  const int o = tid - c * OUTd;
  const bool active = tid < 160;
  float a2 = 0.f, oma2 = 0.f;
  if (active) {
    a2 = 1.f / (1.f + expf(-tau_m2[o]));
    oma2 = 1.f - a2;
  }
  const float* Rb = R + (size_t)b * Td * OUTd;
  float* Ob = out + (size_t)b * Td * OUTd;
  const int t0 = c * 125;

  if (active) {
    float m = 0.f;
    for (int u = 0; u < 125; ++u)
      m = a2 * m + oma2 * Rb[(size_t)(t0 + u) * OUTd + o];
    leS[c][o] = m;
  }
  __syncthreads();
  if (tid < OUTd) {
    const float a = 1.f / (1.f + expf(-tau_m2[tid]));
    float aL = 1.f;
    for (int i = 0; i < 125; ++i) aL *= a;
    float m = mem2_0[b * OUTd + tid];
    for (int cc = 0; cc < 8; ++cc) {
      stS[cc][tid] = m;
      m = aL * m + leS[cc][tid];
    }
  }
  __syncthreads();
  if (active) {
    float m = stS[c][o];
    for (int u = 0; u < 125; ++u) {
      m = a2 * m + oma2 * Rb[(size_t)(t0 + u) * OUTd + o];
      Ob[(size_t)(t0 + u) * OUTd + o] = m;
    }
  }
}

extern "C" void kernel_launch(void* const* d_in, const int* in_sizes, int n_in,
                              void* d_out, int out_size, void* d_ws, size_t ws_size,
                              hipStream_t stream) {
  const float* x      = (const float*)d_in[0];
  const float* W1     = (const float*)d_in[1];
  const float* b1     = (const float*)d_in[2];
  const float* tau_m1 = (const float*)d_in[3];
  const float* tau_n1 = (const float*)d_in[4];
  const float* W2     = (const float*)d_in[5];
  const float* b2     = (const float*)d_in[6];
  const float* tau_m2 = (const float*)d_in[7];
  const float* mem1_0 = (const float*)d_in[8];
  const float* mem2_0 = (const float*)d_in[9];
  float* out = (float*)d_out;

  const size_t proj_b = (size_t)Md * Hd * sizeof(float);            // 262.1 MB
  const size_t xp_b   = (size_t)Md * KH * sizeof(f16);              // 360.4 MB
  const size_t wp_b   = (size_t)512 * KH * sizeof(f16);             // 1.44 MB
  const size_t spk_b  = (size_t)Md * 8 * sizeof(unsigned long long);// 8.2 MB

  float* proj = (float*)d_ws;

  if (ws_size >= proj_b + xp_b + wp_b) {
    // Fast path: proj | Xp | Wp.  spk+R overlay the Xp region after gemm1.
    f16* Xpk = (f16*)((char*)d_ws + proj_b);
    f16* Wpk = (f16*)((char*)d_ws + proj_b + xp_b);
    unsigned long long* spk = (unsigned long long*)((char*)d_ws + proj_b);
    float* R = (float*)((char*)d_ws + proj_b + spk_b);

    pack_kernel<<<dim3(((Md + 512) * 88 + 255) / 256), 256, 0, stream>>>(
        x, W1, Xpk, Wpk);
    gemm1_kernel<<<dim3((Hd / 256) * (Md / 256)), 512, 0, stream>>>(Xpk, Wpk,
                                                                    b1, proj);
    scan1_kernel<<<dim3(Bd * Hd / 256), 256, 0, stream>>>(proj, tau_m1, tau_n1,
                                                          mem1_0, spk);
    gemm2_kernel<<<dim3((Md + 95) / 96), 256, 0, stream>>>(spk, W2, b2, R, Md);
    scan2_kernel<<<dim3(Bd), 256, 0, stream>>>(R, tau_m2, mem2_0, out);
  } else {
    // Fallback (previous verified layout): proj | spk | R, W1 splits inside R.
    unsigned long long* spk =
        (unsigned long long*)((char*)d_ws + proj_b);
    float* R = (float*)((char*)spk + spk_b);
    f16* W1a = (f16*)R;
    f16* W1b = W1a + 512 * KPAD;

    w1split_kernel<<<dim3((512 * KPAD + 255) / 256), 256, 0, stream>>>(W1, W1a,
                                                                       W1b);
    gemm1_fb_kernel<<<dim3(Hd / 128, Md / 128), 256, 0, stream>>>(x, W1a, W1b,
                                                                  b1, proj);
    scan1_kernel<<<dim3(Bd * Hd / 256), 256, 0, stream>>>(proj, tau_m1, tau_n1,
                                                          mem1_0, spk);
    gemm2_kernel<<<dim3((Md + 95) / 96), 256, 0, stream>>>(spk, W2, b2, R, Md);
    scan2_kernel<<<dim3(Bd), 256, 0, stream>>>(R, tau_m2, mem2_0, out);
  }
}